// Round 1
// baseline (1207.966 us; speedup 1.0000x reference)
//
#include <hip/hip_runtime.h>

// LightGNN: 3-layer LGConv accumulation.
// out = (x + c1 + c2 + c3)/4, x = emb[n_id], c_k = LGConv(c_{k-1})
// LGConv: deg=in-deg(col); dinv=rsqrt(deg) (0 if deg==0);
//         next[col] += cur[row] * dinv[row]*dinv[col]

#define D 64

__global__ void deg_kernel(const int* __restrict__ col, float* __restrict__ deg, int E) {
    int e = blockIdx.x * blockDim.x + threadIdx.x;
    if (e < E) atomicAdd(&deg[col[e]], 1.0f);
}

__global__ void dinv_kernel(float* __restrict__ deg, int N) {
    int i = blockIdx.x * blockDim.x + threadIdx.x;
    if (i < N) {
        float d = deg[i];
        deg[i] = (d > 0.0f) ? rsqrtf(d) : 0.0f;
    }
}

// t = i*64 + d ; cur = x, out = 0.25*x
__global__ void gather_kernel(const int* __restrict__ n_id, const float* __restrict__ emb,
                              float* __restrict__ cur, float* __restrict__ out, int N) {
    int t = blockIdx.x * blockDim.x + threadIdx.x;
    if (t < N * D) {
        int i = t >> 6;
        int d = t & 63;
        float v = emb[(long long)n_id[i] * D + d];
        cur[t] = v;
        out[t] = 0.25f * v;
    }
}

// one wave per edge: lane d handles element d (coalesced read + coalesced atomic)
__global__ void scatter_kernel(const int* __restrict__ row, const int* __restrict__ col,
                               const float* __restrict__ dinv, const float* __restrict__ cur,
                               float* __restrict__ nxt, int E) {
    long long t = (long long)blockIdx.x * blockDim.x + threadIdx.x;
    if (t < (long long)E * D) {
        int e = (int)(t >> 6);
        int d = (int)(t & 63);
        int r = row[e];
        int c = col[e];
        float norm = dinv[r] * dinv[c];
        atomicAdd(&nxt[c * D + d], cur[r * D + d] * norm);
    }
}

__global__ void acc_kernel(const float* __restrict__ nxt, float* __restrict__ out, int N) {
    int t = blockIdx.x * blockDim.x + threadIdx.x;
    if (t < N * D) out[t] += 0.25f * nxt[t];
}

extern "C" void kernel_launch(void* const* d_in, const int* in_sizes, int n_in,
                              void* d_out, int out_size, void* d_ws, size_t ws_size,
                              hipStream_t stream) {
    const int*   n_id = (const int*)d_in[0];
    const int*   edge = (const int*)d_in[1];   // [2, E] flat: row = edge[0:E], col = edge[E:2E]
    const float* emb  = (const float*)d_in[3];
    float* out = (float*)d_out;

    const int N = in_sizes[0];
    const int E = in_sizes[1] / 2;
    const int* row = edge;
    const int* col = edge + E;

    // workspace layout: dinv [N] | cur [N*D] | nxt [N*D]
    float* dinv = (float*)d_ws;
    float* cur  = dinv + ((N + 255) & ~255);
    float* nxt  = cur + (size_t)N * D;

    const int BS = 256;

    // 1. degree -> dinv (in place)
    hipMemsetAsync(dinv, 0, (size_t)N * sizeof(float), stream);
    deg_kernel<<<(E + BS - 1) / BS, BS, 0, stream>>>(col, dinv, E);
    dinv_kernel<<<(N + BS - 1) / BS, BS, 0, stream>>>(dinv, N);

    // 2. gather x -> cur, out = x/4
    gather_kernel<<<((size_t)N * D + BS - 1) / BS, BS, 0, stream>>>(n_id, emb, cur, out, N);

    // 3. three LGConv layers
    for (int layer = 0; layer < 3; ++layer) {
        hipMemsetAsync(nxt, 0, (size_t)N * D * sizeof(float), stream);
        long long total = (long long)E * D;
        scatter_kernel<<<(total + BS - 1) / BS, BS, 0, stream>>>(row, col, dinv, cur, nxt, E);
        acc_kernel<<<((size_t)N * D + BS - 1) / BS, BS, 0, stream>>>(nxt, out, N);
        // swap cur/nxt
        float* tmp = cur; cur = nxt; nxt = tmp;
    }
}

// Round 2
// 489.666 us; speedup vs baseline: 2.4669x; 2.4669x over previous
//
#include <hip/hip_runtime.h>
#include <hip/hip_bf16.h>

// LightGNN: out = (x + c1 + c2 + c3)/4, x = emb[n_id], c_k = LGConv(c_{k-1})
// LGConv: deg=in-deg(col); dinv=rsqrt(deg) (0 if deg==0);
//         next[col] = dinv[col] * sum_{(r,col) in E} (cur[r]*dinv[r])
// CSR-by-col + gather (no fp32 atomics). y := cur*dinv stored bf16.

#define D 64

// ---- degree histogram (int atomics) ----
__global__ void deg_kernel(const int* __restrict__ col, int* __restrict__ deg, int E) {
    int e = blockIdx.x * blockDim.x + threadIdx.x;
    if (e < E) atomicAdd(&deg[col[e]], 1);
}

__global__ void dinv_kernel(const int* __restrict__ deg, float* __restrict__ dinv, int N) {
    int i = blockIdx.x * blockDim.x + threadIdx.x;
    if (i < N) {
        int d = deg[i];
        dinv[i] = (d > 0) ? rsqrtf((float)d) : 0.0f;
    }
}

// ---- hierarchical exclusive scan: 1024 elems per block ----
__global__ void scan1_kernel(const int* __restrict__ deg, int* __restrict__ part,
                             int* __restrict__ bsum, int N) {
    __shared__ int sm[256];
    int t = threadIdx.x;
    int base = blockIdx.x * 1024 + t * 4;
    int v[4]; int s = 0;
    for (int k = 0; k < 4; ++k) { int idx = base + k; v[k] = (idx < N) ? deg[idx] : 0; s += v[k]; }
    sm[t] = s; __syncthreads();
    for (int off = 1; off < 256; off <<= 1) {
        int x = (t >= off) ? sm[t - off] : 0;
        __syncthreads();
        sm[t] += x;
        __syncthreads();
    }
    int excl = sm[t] - s;
    if (t == 255) bsum[blockIdx.x] = sm[255];
    int run = excl;
    for (int k = 0; k < 4; ++k) { int idx = base + k; if (idx < N) part[idx] = run; run += v[k]; }
}

__global__ void scan2_kernel(int* __restrict__ bsum, int NB) {
    __shared__ int sm[256];
    int t = threadIdx.x;
    int v = (t < NB) ? bsum[t] : 0;
    sm[t] = v; __syncthreads();
    for (int off = 1; off < 256; off <<= 1) {
        int x = (t >= off) ? sm[t - off] : 0;
        __syncthreads();
        sm[t] += x;
        __syncthreads();
    }
    if (t < NB) bsum[t] = sm[t] - v;   // exclusive
}

__global__ void scan3_kernel(int* __restrict__ colptr, const int* __restrict__ bsum,
                             int* __restrict__ work, int N, int E) {
    int i = blockIdx.x * blockDim.x + threadIdx.x;
    if (i < N) {
        int v = colptr[i] + bsum[i >> 10];
        colptr[i] = v;
        work[i] = v;
    }
    if (i == 0) colptr[N] = E;
}

// ---- bucket scatter: edges sorted by col ----
__global__ void bucket_kernel(const int* __restrict__ row, const int* __restrict__ col,
                              int* __restrict__ work, int* __restrict__ rs, int E) {
    int e = blockIdx.x * blockDim.x + threadIdx.x;
    if (e < E) {
        int c = col[e];
        int p = atomicAdd(&work[c], 1);
        rs[p] = row[e];
    }
}

// ---- embedding gather: out = x/4, y = x*dinv (bf16) ----
__global__ void gather0_kernel(const int* __restrict__ n_id, const float* __restrict__ emb,
                               const float* __restrict__ dinv, __hip_bfloat16* __restrict__ y,
                               float* __restrict__ out, int N) {
    int t = blockIdx.x * blockDim.x + threadIdx.x;
    if (t < N * D) {
        int i = t >> 6;
        int d = t & 63;
        float v = emb[(long long)n_id[i] * D + d];
        out[t] = 0.25f * v;
        y[t] = __float2bfloat16(v * dinv[i]);
    }
}

// ---- LGConv layer: one wave per node, lane = dim ----
template <bool WRITE_Y>
__global__ void layer_kernel(const int* __restrict__ colptr, const int* __restrict__ rs,
                             const float* __restrict__ dinv,
                             const __hip_bfloat16* __restrict__ y,
                             __hip_bfloat16* __restrict__ ynext,
                             float* __restrict__ out, int N) {
    int node = blockIdx.x * 4 + (threadIdx.x >> 6);
    int d = threadIdx.x & 63;
    if (node >= N) return;
    int s = colptr[node];
    int e = colptr[node + 1];
    float a0 = 0.0f, a1 = 0.0f;
    int i = s;
    for (; i + 1 < e; i += 2) {
        int r0 = rs[i];
        int r1 = rs[i + 1];
        a0 += __bfloat162float(y[r0 * D + d]);
        a1 += __bfloat162float(y[r1 * D + d]);
    }
    if (i < e) a0 += __bfloat162float(y[rs[i] * D + d]);
    float di = dinv[node];
    float sum = (a0 + a1) * di;           // = nxt[node][d]
    out[node * D + d] += 0.25f * sum;
    if (WRITE_Y) ynext[node * D + d] = __float2bfloat16(sum * di);
}

extern "C" void kernel_launch(void* const* d_in, const int* in_sizes, int n_in,
                              void* d_out, int out_size, void* d_ws, size_t ws_size,
                              hipStream_t stream) {
    const int*   n_id = (const int*)d_in[0];
    const int*   edge = (const int*)d_in[1];   // [2,E] flat
    const float* emb  = (const float*)d_in[3];
    float* out = (float*)d_out;

    const int N = in_sizes[0];
    const int E = in_sizes[1] / 2;
    const int* row = edge;
    const int* col = edge + E;

    // workspace layout (256B aligned chunks)
    char* p = (char*)d_ws;
    auto alloc = [&](size_t bytes) { char* r = p; p += (bytes + 255) & ~(size_t)255; return r; };
    int*   deg    = (int*)  alloc((size_t)N * 4);
    float* dinv   = (float*)alloc((size_t)N * 4);
    int*   colptr = (int*)  alloc((size_t)(N + 1) * 4);
    int*   work   = (int*)  alloc((size_t)N * 4);
    int*   bsum   = (int*)  alloc(1024 * 4);
    int*   rs     = (int*)  alloc((size_t)E * 4);
    __hip_bfloat16* yA = (__hip_bfloat16*)alloc((size_t)N * D * 2);
    __hip_bfloat16* yB = (__hip_bfloat16*)alloc((size_t)N * D * 2);

    const int BS = 256;
    const int NB = (N + 1023) / 1024;

    // 1. degree + dinv
    hipMemsetAsync(deg, 0, (size_t)N * 4, stream);
    deg_kernel<<<(E + BS - 1) / BS, BS, 0, stream>>>(col, deg, E);
    dinv_kernel<<<(N + BS - 1) / BS, BS, 0, stream>>>(deg, dinv, N);

    // 2. exclusive scan -> colptr, work copy
    scan1_kernel<<<NB, BS, 0, stream>>>(deg, colptr, bsum, N);
    scan2_kernel<<<1, BS, 0, stream>>>(bsum, NB);
    scan3_kernel<<<(N + BS - 1) / BS, BS, 0, stream>>>(colptr, bsum, work, N, E);

    // 3. bucket edges by col
    bucket_kernel<<<(E + BS - 1) / BS, BS, 0, stream>>>(row, col, work, rs, E);

    // 4. embedding gather
    gather0_kernel<<<((size_t)N * D + BS - 1) / BS, BS, 0, stream>>>(n_id, emb, dinv, yA, out, N);

    // 5. three LGConv layers (gather form)
    const int LGRID = (N + 3) / 4;
    layer_kernel<true ><<<LGRID, BS, 0, stream>>>(colptr, rs, dinv, yA, yB, out, N);
    layer_kernel<true ><<<LGRID, BS, 0, stream>>>(colptr, rs, dinv, yB, yA, out, N);
    layer_kernel<false><<<LGRID, BS, 0, stream>>>(colptr, rs, dinv, yA, yB, out, N);
}

// Round 4
// 354.171 us; speedup vs baseline: 3.4107x; 1.3826x over previous
//
#include <hip/hip_runtime.h>

// LightGNN: out = (x + c1 + c2 + c3)/4, x = emb[n_id], c_k = LGConv(c_{k-1})
// LGConv: deg=in-deg(col); dinv=rsqrt(deg) (0 if deg==0);
//         next[col] = dinv[col] * sum_{(r,col) in E} (cur[r]*dinv[r])
// CSR-by-col + wave-per-node gather. y := cur*dinv stored bf16 (row = 32 u32).

#define D 64

typedef unsigned int u32;

__device__ inline float bf16lo(u32 u) { union { u32 i; float f; } c; c.i = u << 16; return c.f; }
__device__ inline float bf16hi(u32 u) { union { u32 i; float f; } c; c.i = u & 0xffff0000u; return c.f; }
__device__ inline u32 f2bf(float f) {            // RNE f32 -> bf16 (low 16 bits)
    union { float f; u32 i; } c; c.f = f;
    return (c.i + 0x7fffu + ((c.i >> 16) & 1u)) >> 16;
}

// ---- degree histogram (int atomics) ----
__global__ void deg_kernel(const int* __restrict__ col, int* __restrict__ deg, int E) {
    int e = blockIdx.x * blockDim.x + threadIdx.x;
    if (e < E) atomicAdd(&deg[col[e]], 1);
}

__global__ void dinv_kernel(const int* __restrict__ deg, float* __restrict__ dinv, int N) {
    int i = blockIdx.x * blockDim.x + threadIdx.x;
    if (i < N) {
        int d = deg[i];
        dinv[i] = (d > 0) ? rsqrtf((float)d) : 0.0f;
    }
}

// ---- hierarchical exclusive scan: 1024 elems per block ----
__global__ void scan1_kernel(const int* __restrict__ deg, int* __restrict__ part,
                             int* __restrict__ bsum, int N) {
    __shared__ int sm[256];
    int t = threadIdx.x;
    int base = blockIdx.x * 1024 + t * 4;
    int v[4]; int s = 0;
    for (int k = 0; k < 4; ++k) { int idx = base + k; v[k] = (idx < N) ? deg[idx] : 0; s += v[k]; }
    sm[t] = s; __syncthreads();
    for (int off = 1; off < 256; off <<= 1) {
        int x = (t >= off) ? sm[t - off] : 0;
        __syncthreads();
        sm[t] += x;
        __syncthreads();
    }
    int excl = sm[t] - s;
    if (t == 255) bsum[blockIdx.x] = sm[255];
    int run = excl;
    for (int k = 0; k < 4; ++k) { int idx = base + k; if (idx < N) part[idx] = run; run += v[k]; }
}

__global__ void scan2_kernel(int* __restrict__ bsum, int NB) {
    __shared__ int sm[256];
    int t = threadIdx.x;
    int v = (t < NB) ? bsum[t] : 0;
    sm[t] = v; __syncthreads();
    for (int off = 1; off < 256; off <<= 1) {
        int x = (t >= off) ? sm[t - off] : 0;
        __syncthreads();
        sm[t] += x;
        __syncthreads();
    }
    if (t < NB) bsum[t] = sm[t] - v;   // exclusive
}

__global__ void scan3_kernel(int* __restrict__ colptr, const int* __restrict__ bsum,
                             int* __restrict__ work, int N, int E) {
    int i = blockIdx.x * blockDim.x + threadIdx.x;
    if (i < N) {
        int v = colptr[i] + bsum[i >> 10];
        colptr[i] = v;
        work[i] = v;
    }
    if (i == 0) colptr[N] = E;
}

// ---- bucket scatter: edges sorted by col ----
__global__ void bucket_kernel(const int* __restrict__ row, const int* __restrict__ col,
                              int* __restrict__ work, int* __restrict__ rs, int E) {
    int e = blockIdx.x * blockDim.x + threadIdx.x;
    if (e < E) {
        int c = col[e];
        int p = atomicAdd(&work[c], 1);
        rs[p] = row[e];
    }
}

// ---- embedding gather: out = x/4, y = x*dinv (bf16). 16 lanes per row. ----
__global__ void gather0_kernel(const int* __restrict__ n_id, const float4* __restrict__ emb,
                               const float* __restrict__ dinv, uint2* __restrict__ y,
                               float4* __restrict__ out, int N) {
    int t = blockIdx.x * blockDim.x + threadIdx.x;
    if (t >= N * 16) return;
    int i = t >> 4, q = t & 15;
    float4 v = emb[(size_t)n_id[i] * 16 + q];
    float4 o; o.x = 0.25f * v.x; o.y = 0.25f * v.y; o.z = 0.25f * v.z; o.w = 0.25f * v.w;
    out[(size_t)i * 16 + q] = o;
    float di = dinv[i];
    uint2 p;
    p.x = f2bf(v.x * di) | (f2bf(v.y * di) << 16);
    p.y = f2bf(v.z * di) | (f2bf(v.w * di) << 16);
    y[(size_t)i * 16 + q] = p;
}

// ---- LGConv layer: wave = node; lane = (edge-group l>>3, dim-octet l&7) ----
// Each lane loads uint4 = 8 bf16 (16 B); wave consumes 8 edges x 128 B per iter.
template <bool WRITE_Y>
__global__ void layer_kernel(const int* __restrict__ colptr, const int* __restrict__ rs,
                             const float* __restrict__ dinv,
                             const u32* __restrict__ y,      // row stride 32 u32
                             u32* __restrict__ ynext,
                             float* __restrict__ out, int N) {
    int node = blockIdx.x * 4 + (threadIdx.x >> 6);
    if (node >= N) return;
    int lane = threadIdx.x & 63;
    int egrp = lane >> 3;      // 0..7
    int oct  = lane & 7;       // dims 8*oct .. 8*oct+7
    int s = colptr[node], e = colptr[node + 1];
    float a[8] = {0, 0, 0, 0, 0, 0, 0, 0};
    for (int i = s + egrp; i < e; i += 8) {
        int r = rs[i];
        uint4 w = *((const uint4*)(y + (size_t)r * 32) + oct);
        a[0] += bf16lo(w.x); a[1] += bf16hi(w.x);
        a[2] += bf16lo(w.y); a[3] += bf16hi(w.y);
        a[4] += bf16lo(w.z); a[5] += bf16hi(w.z);
        a[6] += bf16lo(w.w); a[7] += bf16hi(w.w);
    }
    #pragma unroll
    for (int m = 8; m <= 32; m <<= 1) {
        #pragma unroll
        for (int k = 0; k < 8; ++k) a[k] += __shfl_xor(a[k], m, 64);
    }
    if (lane < 8) {
        float di = dinv[node];
        float o[8];
        #pragma unroll
        for (int k = 0; k < 8; ++k) o[k] = a[k] * di;     // nxt[node][8*oct+k]
        float4* op = (float4*)(out + (size_t)node * D) + oct * 2;
        float4 c0 = op[0], c1 = op[1];
        c0.x += 0.25f * o[0]; c0.y += 0.25f * o[1]; c0.z += 0.25f * o[2]; c0.w += 0.25f * o[3];
        c1.x += 0.25f * o[4]; c1.y += 0.25f * o[5]; c1.z += 0.25f * o[6]; c1.w += 0.25f * o[7];
        op[0] = c0; op[1] = c1;
        if (WRITE_Y) {
            uint4 w;
            w.x = f2bf(o[0] * di) | (f2bf(o[1] * di) << 16);
            w.y = f2bf(o[2] * di) | (f2bf(o[3] * di) << 16);
            w.z = f2bf(o[4] * di) | (f2bf(o[5] * di) << 16);
            w.w = f2bf(o[6] * di) | (f2bf(o[7] * di) << 16);
            *((uint4*)(ynext + (size_t)node * 32) + oct) = w;
        }
    }
}

extern "C" void kernel_launch(void* const* d_in, const int* in_sizes, int n_in,
                              void* d_out, int out_size, void* d_ws, size_t ws_size,
                              hipStream_t stream) {
    const int*    n_id = (const int*)d_in[0];
    const int*    edge = (const int*)d_in[1];   // [2,E] flat
    const float*  emb  = (const float*)d_in[3];
    float* out = (float*)d_out;

    const int N = in_sizes[0];
    const int E = in_sizes[1] / 2;
    const int* row = edge;
    const int* col = edge + E;

    // workspace layout (256B aligned chunks)
    char* p = (char*)d_ws;
    auto alloc = [&](size_t bytes) { char* r = p; p += (bytes + 255) & ~(size_t)255; return r; };
    int*   deg    = (int*)  alloc((size_t)N * 4);
    float* dinv   = (float*)alloc((size_t)N * 4);
    int*   colptr = (int*)  alloc((size_t)(N + 1) * 4);
    int*   work   = (int*)  alloc((size_t)N * 4);
    int*   bsum   = (int*)  alloc(1024 * 4);
    int*   rs     = (int*)  alloc((size_t)E * 4);
    u32*   yA     = (u32*)  alloc((size_t)N * D * 2);
    u32*   yB     = (u32*)  alloc((size_t)N * D * 2);

    const int BS = 256;
    const int NB = (N + 1023) / 1024;

    // 1. degree + dinv
    hipMemsetAsync(deg, 0, (size_t)N * 4, stream);
    deg_kernel<<<(E + BS - 1) / BS, BS, 0, stream>>>(col, deg, E);
    dinv_kernel<<<(N + BS - 1) / BS, BS, 0, stream>>>(deg, dinv, N);

    // 2. exclusive scan -> colptr, work copy
    scan1_kernel<<<NB, BS, 0, stream>>>(deg, colptr, bsum, N);
    scan2_kernel<<<1, BS, 0, stream>>>(bsum, NB);
    scan3_kernel<<<(N + BS - 1) / BS, BS, 0, stream>>>(colptr, bsum, work, N, E);

    // 3. bucket edges by col
    bucket_kernel<<<(E + BS - 1) / BS, BS, 0, stream>>>(row, col, work, rs, E);

    // 4. embedding gather
    gather0_kernel<<<((size_t)N * 16 + BS - 1) / BS, BS, 0, stream>>>(
        n_id, (const float4*)emb, dinv, (uint2*)yA, (float4*)out, N);

    // 5. three LGConv layers (gather form)
    const int LGRID = (N + 3) / 4;
    layer_kernel<true ><<<LGRID, BS, 0, stream>>>(colptr, rs, dinv, yA, yB, out, N);
    layer_kernel<true ><<<LGRID, BS, 0, stream>>>(colptr, rs, dinv, yB, yA, out, N);
    layer_kernel<false><<<LGRID, BS, 0, stream>>>(colptr, rs, dinv, yA, yB, out, N);
}